// Round 3
// baseline (229.576 us; speedup 1.0000x reference)
//
#include <hip/hip_runtime.h>
#include <hip/hip_bf16.h>

constexpr int IN_DIM  = 128;
constexpr int HID     = 256;
constexpr int OUT_DIM = 128;
constexpr int ELL_W   = 64;    // max in-degree slots; Poisson(12) => P(overflow) ~ 1e-24

typedef __attribute__((ext_vector_type(8))) short short8;
typedef __attribute__((ext_vector_type(8))) unsigned short ushort8;
typedef __attribute__((ext_vector_type(4))) float f32x4;

__device__ __forceinline__ float bf2f(unsigned short u) {
    return __uint_as_float(((unsigned int)u) << 16);
}
__device__ __forceinline__ unsigned short f2bf(float f) {
    unsigned int u = __float_as_uint(f);
    u += 0x7FFFu + ((u >> 16) & 1u);      // RNE
    return (unsigned short)(u >> 16);
}
__device__ __forceinline__ unsigned short f2h(float f) {
    _Float16 h = (_Float16)f;             // v_cvt_f16_f32, RNE
    unsigned short b;
    __builtin_memcpy(&b, &h, 2);
    return b;
}
__device__ __forceinline__ float h2f(unsigned short b) {
    _Float16 h;
    __builtin_memcpy(&h, &b, 2);
    return (float)h;
}
// ELL entry: low16 = src node id (n < 65536), high16 = fp16 edge weight
__device__ __forceinline__ unsigned int pack_e(int src, float w) {
    return (unsigned int)src | ((unsigned int)f2h(w) << 16);
}

// Shared ELL-gather core: one node per 16-lane group (gw = group-in-wave 0..3).
// Metadata loaded coalesced 16 slots at a time, distributed via __shfl; edge rows
// consumed in pairs with a 1-deep prefetch pipeline. OOB meta slots are 0
// (weight fp16(0) = 0) so spurious pipeline loads are harmless row-0 reads.
__device__ __forceinline__ void ell_gather_acc(
    const unsigned int* __restrict__ bucket, int m,
    const unsigned short* __restrict__ tab, int j8, int gw, int l16,
    float acc[8]) {
    for (int base = 0; base < m; base += 16) {
        const unsigned int mt = (base + l16 < m) ? bucket[base + l16] : 0u;
        const int c16   = min(m - base, 16);
        const int pairs = (c16 + 1) >> 1;
        unsigned int u0 = __shfl(mt, gw * 16 + 0);
        unsigned int u1 = __shfl(mt, gw * 16 + 1);
        ushort8 v0 = *(const ushort8*)&tab[(size_t)(u0 & 0xFFFFu) * 128 + j8];
        ushort8 v1 = *(const ushort8*)&tab[(size_t)(u1 & 0xFFFFu) * 128 + j8];
        for (int p = 1; p < pairs; ++p) {
            const unsigned int n0 = __shfl(mt, gw * 16 + 2 * p);
            const unsigned int n1 = __shfl(mt, gw * 16 + 2 * p + 1);
            const ushort8 w0 = *(const ushort8*)&tab[(size_t)(n0 & 0xFFFFu) * 128 + j8];
            const ushort8 w1 = *(const ushort8*)&tab[(size_t)(n1 & 0xFFFFu) * 128 + j8];
            const float f0 = h2f((unsigned short)(u0 >> 16));
            const float f1 = h2f((unsigned short)(u1 >> 16));
            #pragma unroll
            for (int i = 0; i < 8; ++i) acc[i] = fmaf(f0, bf2f(v0[i]), acc[i]);
            #pragma unroll
            for (int i = 0; i < 8; ++i) acc[i] = fmaf(f1, bf2f(v1[i]), acc[i]);
            u0 = n0; u1 = n1; v0 = w0; v1 = w1;
        }
        const float f0 = h2f((unsigned short)(u0 >> 16));
        const float f1 = h2f((unsigned short)(u1 >> 16));
        #pragma unroll
        for (int i = 0; i < 8; ++i) acc[i] = fmaf(f0, bf2f(v0[i]), acc[i]);
        #pragma unroll
        for (int i = 0; i < 8; ++i) acc[i] = fmaf(f1, bf2f(v1[i]), acc[i]);
    }
}

// ---------------- prep: zero cnt/deg + transpose/convert W1,W2 to bf16 [N][K] ----------------
__global__ void k_prep(int* __restrict__ cnt, float* __restrict__ deg, int n,
                       const float* __restrict__ W1, unsigned short* __restrict__ w1t,
                       const float* __restrict__ W2, unsigned short* __restrict__ w2t) {
    const int i = blockIdx.x * 256 + threadIdx.x;
    if (i < n) { cnt[i] = 0; deg[i] = 0.f; }
    if (i < IN_DIM * HID) {                      // W1[128][256] -> w1t[256][128]
        const int k = i / HID, nn = i % HID;
        w1t[(size_t)nn * IN_DIM + k] = f2bf(W1[i]);
    }
    if (i < HID * OUT_DIM) {                     // W2[256][128] -> w2t[128][256]
        const int k = i / OUT_DIM, nn = i % OUT_DIM;
        w2t[(size_t)nn * HID + k] = f2bf(W2[i]);
    }
}

// ---------------- ELL fill: 4 edges per thread + f32 degree accumulation ----------------
__global__ void k_fill_ell(const int* __restrict__ row, const int* __restrict__ col,
                           const float* __restrict__ ew, int* __restrict__ cnt,
                           float* __restrict__ deg, unsigned int* __restrict__ ell, int E) {
    const int i  = blockIdx.x * blockDim.x + threadIdx.x;
    const int e0 = i * 4;
    if (e0 + 3 < E) {
        const int4   c4 = *reinterpret_cast<const int4*>(col + e0);
        const int4   r4 = *reinterpret_cast<const int4*>(row + e0);
        const float4 w4 = *reinterpret_cast<const float4*>(ew + e0);
        const int p0 = atomicAdd(&cnt[c4.x], 1);
        const int p1 = atomicAdd(&cnt[c4.y], 1);
        const int p2 = atomicAdd(&cnt[c4.z], 1);
        const int p3 = atomicAdd(&cnt[c4.w], 1);
        atomicAdd(&deg[c4.x], w4.x);
        atomicAdd(&deg[c4.y], w4.y);
        atomicAdd(&deg[c4.z], w4.z);
        atomicAdd(&deg[c4.w], w4.w);
        if (p0 < ELL_W) ell[(size_t)c4.x * ELL_W + p0] = pack_e(r4.x, w4.x);
        if (p1 < ELL_W) ell[(size_t)c4.y * ELL_W + p1] = pack_e(r4.y, w4.y);
        if (p2 < ELL_W) ell[(size_t)c4.z * ELL_W + p2] = pack_e(r4.z, w4.z);
        if (p3 < ELL_W) ell[(size_t)c4.w * ELL_W + p3] = pack_e(r4.w, w4.w);
    } else {
        for (int e = e0; e < E; ++e) {
            const int c = col[e];
            const int p = atomicAdd(&cnt[c], 1);
            atomicAdd(&deg[c], ew[e]);
            if (p < ELL_W) ell[(size_t)c * ELL_W + p] = pack_e(row[e], ew[e]);
        }
    }
}

// ---------------- dinv = rsqrt(1+deg); xs = bf16(dinv * x) (wave per node) ----------------
__global__ __launch_bounds__(256)
void k_deg_xs(const float* __restrict__ deg, const float* __restrict__ x,
              float* __restrict__ dinv, unsigned short* __restrict__ xs, int n) {
    const int wave = threadIdx.x >> 6;
    const int lane = threadIdx.x & 63;
    const int node = blockIdx.x * 4 + wave;
    if (node >= n) return;
    const float di = rsqrtf(1.0f + deg[node]);   // self-loop weight 1
    if (lane == 0) dinv[node] = di;
    const float2 v = *reinterpret_cast<const float2*>(x + (size_t)node * IN_DIM + lane * 2);
    const unsigned int packed = (unsigned int)f2bf(v.x * di) |
                                ((unsigned int)f2bf(v.y * di) << 16);
    *reinterpret_cast<unsigned int*>(xs + (size_t)node * IN_DIM + lane * 2) = packed;
}

// ---------------- gather: node per 16-lane group, 16 nodes/block (F=128) ----------------
// hs rows pre-scaled by dinv[src]. out[c] = post( dinv[c]*(hs[c] + sum ew*hs[src]) )
template<bool BIAS_RELU, bool BF16OUT>
__global__ __launch_bounds__(256)
void k_gather_w(const int* __restrict__ cnt, const unsigned int* __restrict__ ell,
                const float* __restrict__ dinv, const unsigned short* __restrict__ hs,
                const float* __restrict__ bias, void* __restrict__ out_, int n) {
    constexpr int F = 128;
    const int gid  = threadIdx.x >> 4;           // 0..15 group in block
    const int gw   = gid & 3;                    // group in wave
    const int l16  = threadIdx.x & 15;
    const int j8   = l16 * 8;
    const int node = blockIdx.x * 16 + gid;
    if (node >= n) return;

    const int m = min(cnt[node], ELL_W);
    const unsigned int* bucket = ell + (size_t)node * ELL_W;

    float acc[8] = {};
    ell_gather_acc(bucket, m, hs, j8, gw, l16, acc);

    const float dc = dinv[node];
    const ushort8 hv = *reinterpret_cast<const ushort8*>(hs + (size_t)node * F + j8);
    float o[8];
    if (BIAS_RELU) {
        const float4 b0 = *reinterpret_cast<const float4*>(bias + j8);
        const float4 b1 = *reinterpret_cast<const float4*>(bias + j8 + 4);
        const float bb[8] = {b0.x, b0.y, b0.z, b0.w, b1.x, b1.y, b1.z, b1.w};
        #pragma unroll
        for (int i = 0; i < 8; ++i)
            o[i] = fmaxf(fmaf(dc, acc[i] + bf2f(hv[i]), bb[i]), 0.f);
    } else {
        #pragma unroll
        for (int i = 0; i < 8; ++i) o[i] = dc * (acc[i] + bf2f(hv[i]));
    }
    if (BF16OUT) {
        unsigned short ob[8];
        #pragma unroll
        for (int i = 0; i < 8; ++i) ob[i] = f2bf(o[i]);
        *reinterpret_cast<uint4*>((unsigned short*)out_ + (size_t)node * F + j8) =
            *reinterpret_cast<uint4*>(ob);
    } else {
        float* op = (float*)out_ + (size_t)node * F + j8;
        *reinterpret_cast<float4*>(op)     = make_float4(o[0], o[1], o[2], o[3]);
        *reinterpret_cast<float4*>(op + 4) = make_float4(o[4], o[5], o[6], o[7]);
    }
}

// ---- dual GEMM: h2s = dinv * (relu( aggx@W1t^T + b1) @ W2t^T ) ----
// Block = 64 rows, 4 waves. Weight slabs staged one phase ahead through three
// LDS buffers (As/Bs/Hs) so no global_load_lds latency is barrier-exposed.
// All tiles use the rule-21 XOR swizzle (linear LDS dest + pre-swizzled global src,
// XOR on read) to break the 16-way ds_read_b128 bank conflict of 128B-stride rows.
__global__ __launch_bounds__(256)
void k_gemm_dual(const unsigned short* __restrict__ A,    // aggx [Mpad][128] bf16
                 const unsigned short* __restrict__ W1t,  // [256][128] bf16
                 const unsigned short* __restrict__ W2t,  // [128][256] bf16
                 const float* __restrict__ b1,
                 const float* __restrict__ dinv,
                 unsigned short* __restrict__ H2,         // h2s [Mpad][128] bf16
                 int n) {
    __shared__ unsigned short As[64 * 128];    // 16 KB: A tile / W2 slab buffer
    __shared__ unsigned short Bs [256 * 64];   // 32 KB: W1 slab0 / W2 slab buffer
    __shared__ unsigned short Hs [64 * 256];   // 32 KB: W1 slab1 / h1 tile

    const int t    = threadIdx.x;
    const int w    = t >> 6;
    const int lane = t & 63;
    const int quad = lane >> 4;
    const int l16  = lane & 15;
    const int lrow = lane >> 3;                    // row-within-8 for W staging
    const int lcol = ((lane & 7) ^ lrow) * 8;      // pre-swizzled source chunk (elements)
    const int xr   = (l16 & 7) << 3;               // read-side XOR (ushort units)
    const int rowBase = blockIdx.x * 64;

    const unsigned short* gB1 = W1t + (size_t)(w * 64 + lrow) * IN_DIM + lcol;
    const unsigned short* gB2 = W2t + (size_t)(w * 32 + lrow) * HID + lcol;

    auto stageA = [&]() {                          // A tile [64][128], row-XOR swizzled
        #pragma unroll
        for (int j = 0; j < 4; ++j) {
            const int ci = w * 64 + j * 256 + lane;      // dest 16B-chunk index
            const int r  = ci >> 4;                      // tile row
            const int c  = (lane & 15) ^ (r & 7);        // pre-swizzled source chunk
            __builtin_amdgcn_global_load_lds(
                (const __attribute__((address_space(1))) uint32_t*)(A + (size_t)(rowBase + r) * 128 + c * 8),
                (__attribute__((address_space(3))) uint32_t*)(&As[(size_t)ci * 8]), 16, 0, 0);
        }
    };
    auto stageW1 = [&](unsigned short* buf, int k0) {
        #pragma unroll
        for (int j = 0; j < 8; ++j)
            __builtin_amdgcn_global_load_lds(
                (const __attribute__((address_space(1))) uint32_t*)(gB1 + k0 + (size_t)j * 8 * IN_DIM),
                (__attribute__((address_space(3))) uint32_t*)(&buf[(w * 64 + j * 8) * 64]), 16, 0, 0);
    };
    auto stageW2 = [&](unsigned short* buf, int k0) {
        #pragma unroll
        for (int j = 0; j < 4; ++j)
            __builtin_amdgcn_global_load_lds(
                (const __attribute__((address_space(1))) uint32_t*)(gB2 + k0 + (size_t)j * 8 * HID),
                (__attribute__((address_space(3))) uint32_t*)(&buf[(w * 32 + j * 8) * 64]), 16, 0, 0);
    };

    f32x4 acc[4][4] = {};
    auto mma1 = [&](const unsigned short* Bbuf, int k0) {
        #pragma unroll
        for (int ks = 0; ks < 2; ++ks) {
            short8 af[4], bfr[4];
            #pragma unroll
            for (int mt = 0; mt < 4; ++mt)
                af[mt] = *(const short8*)&As[(mt * 16 + l16) * 128 + ((k0 + ks * 32 + quad * 8) ^ xr)];
            #pragma unroll
            for (int nt = 0; nt < 4; ++nt)
                bfr[nt] = *(const short8*)&Bbuf[(w * 64 + nt * 16 + l16) * 64 + ((ks * 32 + quad * 8) ^ xr)];
            #pragma unroll
            for (int mt = 0; mt < 4; ++mt)
                #pragma unroll
                for (int nt = 0; nt < 4; ++nt)
                    acc[mt][nt] = __builtin_amdgcn_mfma_f32_16x16x32_bf16(
                        af[mt], bfr[nt], acc[mt][nt], 0, 0, 0);
        }
    };

    stageA();                        // A tile + W1 slab0 in flight together
    stageW1(Bs, 0);
    __syncthreads();                 // As + Bs ready
    stageW1(Hs, 64);                 // W1 slab1 -> Hs, overlaps k0=0 compute
    mma1(Bs, 0);
    __syncthreads();                 // slab1 ready
    mma1(Hs, 64);
    __syncthreads();                 // all As / Hs-as-W1 reads done

    stageW2(As, 0);                  // W2 slab0 -> As, overlaps epilogue 1

    // ---- epilogue 1: bias + relu -> Hs (bf16 h1 tile, swizzled) ----
    {
        float bv[4];
        #pragma unroll
        for (int nt = 0; nt < 4; ++nt) bv[nt] = b1[w * 64 + nt * 16 + l16];
        #pragma unroll
        for (int mt = 0; mt < 4; ++mt)
            #pragma unroll
            for (int i = 0; i < 4; ++i) {
                const int row = mt * 16 + quad * 4 + i;
                const int xw  = (row & 7) << 3;
                #pragma unroll
                for (int nt = 0; nt < 4; ++nt) {
                    const int col = w * 64 + nt * 16 + l16;
                    Hs[row * 256 + (col ^ xw)] = f2bf(fmaxf(acc[mt][nt][i] + bv[nt], 0.f));
                }
            }
    }

    f32x4 acc2[4][2] = {};
    auto mma2 = [&](const unsigned short* Bbuf, int k0) {
        #pragma unroll
        for (int ks = 0; ks < 2; ++ks) {
            short8 af[4], bfr[2];
            #pragma unroll
            for (int mt = 0; mt < 4; ++mt)
                af[mt] = *(const short8*)&Hs[(mt * 16 + l16) * 256 + ((k0 + ks * 32 + quad * 8) ^ xr)];
            #pragma unroll
            for (int nt = 0; nt < 2; ++nt)
                bfr[nt] = *(const short8*)&Bbuf[(w * 32 + nt * 16 + l16) * 64 + ((ks * 32 + quad * 8) ^ xr)];
            #pragma unroll
            for (int mt = 0; mt < 4; ++mt)
                #pragma unroll
                for (int nt = 0; nt < 2; ++nt)
                    acc2[mt][nt] = __builtin_amdgcn_mfma_f32_16x16x32_bf16(
                        af[mt], bfr[nt], acc2[mt][nt], 0, 0, 0);
        }
    };

    __syncthreads();                 // Hs h1 visible; W2 slab0 ready
    stageW2(Bs, 64);                 // slab1, overlaps slab0 compute
    mma2(As, 0);
    __syncthreads();
    stageW2(As, 128);                // slab2
    mma2(Bs, 64);
    __syncthreads();
    stageW2(Bs, 192);                // slab3
    mma2(As, 128);
    __syncthreads();
    mma2(Bs, 192);

    // ---- epilogue 2: row-scale by dinv, bf16 out ----
    #pragma unroll
    for (int mt = 0; mt < 4; ++mt)
        #pragma unroll
        for (int i = 0; i < 4; ++i) {
            const int r = rowBase + mt * 16 + quad * 4 + i;
            if (r < n) {
                const float dr = dinv[r];
                #pragma unroll
                for (int nt = 0; nt < 2; ++nt) {
                    const int c = w * 32 + nt * 16 + l16;
                    H2[(size_t)r * OUT_DIM + c] = f2bf(acc2[mt][nt][i] * dr);
                }
            }
        }
}

// ---------------- launch ----------------
extern "C" void kernel_launch(void* const* d_in, const int* in_sizes, int n_in,
                              void* d_out, int out_size, void* d_ws, size_t ws_size,
                              hipStream_t stream) {
    const float* x  = (const float*)d_in[0];
    const int*   ei = (const int*)d_in[1];
    const float* ew = (const float*)d_in[2];
    const float* W1 = (const float*)d_in[3];
    const float* b1 = (const float*)d_in[4];
    const float* W2 = (const float*)d_in[5];
    const float* b2 = (const float*)d_in[6];
    float* out = (float*)d_out;

    const int n = in_sizes[0] / IN_DIM;     // 50000  (< 65536, required by ELL packing)
    const int E = in_sizes[1] / 2;          // 600000
    const int Mpad = (n + 127) & ~127;      // 50048
    const int* row = ei;
    const int* col = ei + E;

    float* ws = (float*)d_ws;
    size_t o = 0;
    auto alloc = [&](size_t words) { float* p = ws + o; o += (words + 63) & ~(size_t)63; return p; };
    float* dinv = alloc(n);
    float* deg  = alloc(n);
    int*   cnt  = (int*)alloc(n);
    unsigned int* ell = (unsigned int*)alloc((size_t)n * ELL_W);                  // 12.8 MB
    unsigned short* xs   = (unsigned short*)alloc((size_t)Mpad * IN_DIM / 2);     // bf16 dinv*x
    unsigned short* aggx = (unsigned short*)alloc((size_t)Mpad * IN_DIM / 2);     // bf16 A-hat x
    unsigned short* h2s  = (unsigned short*)alloc((size_t)Mpad * OUT_DIM / 2);    // bf16 dinv*h2
    unsigned short* w1t  = (unsigned short*)alloc((size_t)IN_DIM * HID / 2);
    unsigned short* w2t  = (unsigned short*)alloc((size_t)HID * OUT_DIM / 2);

    // ---- build ----
    k_prep<<<(n + 255) / 256, 256, 0, stream>>>(cnt, deg, n, W1, w1t, W2, w2t);
    k_fill_ell<<<(E / 4 + 255) / 256, 256, 0, stream>>>(row, col, ew, cnt, deg, ell, E);
    k_deg_xs<<<(n + 3) / 4, 256, 0, stream>>>(deg, x, dinv, xs, n);

    // ---- layer 1 aggregate: aggx = dinv*(xs_self + sum ew*xs) ----
    k_gather_w<false, true><<<(n + 15) / 16, 256, 0, stream>>>(cnt, ell, dinv, xs, nullptr, aggx, n);

    // ---- fused GEMMs: h2s = dinv * (relu(aggx@W1 + b1) @ W2) ----
    k_gemm_dual<<<Mpad / 64, 256, 0, stream>>>(aggx, w1t, w2t, b1, dinv, h2s, n);

    // ---- layer 2 aggregate + bias + relu ----
    k_gather_w<true, false><<<(n + 15) / 16, 256, 0, stream>>>(cnt, ell, dinv, h2s, b2, out, n);
}

// Round 4
// 207.646 us; speedup vs baseline: 1.1056x; 1.1056x over previous
//
#include <hip/hip_runtime.h>
#include <hip/hip_bf16.h>

constexpr int IN_DIM  = 128;
constexpr int HID     = 256;
constexpr int OUT_DIM = 128;
constexpr int ELL_W   = 64;    // max in-degree slots; Poisson(12) => P(overflow) ~ 1e-24

typedef __attribute__((ext_vector_type(8))) short short8;
typedef __attribute__((ext_vector_type(8))) unsigned short ushort8;
typedef __attribute__((ext_vector_type(4))) float f32x4;

__device__ __forceinline__ float bf2f(unsigned short u) {
    return __uint_as_float(((unsigned int)u) << 16);
}
__device__ __forceinline__ unsigned short f2bf(float f) {
    unsigned int u = __float_as_uint(f);
    u += 0x7FFFu + ((u >> 16) & 1u);      // RNE
    return (unsigned short)(u >> 16);
}
__device__ __forceinline__ unsigned short f2h(float f) {
    _Float16 h = (_Float16)f;             // v_cvt_f16_f32, RNE
    unsigned short b;
    __builtin_memcpy(&b, &h, 2);
    return b;
}
__device__ __forceinline__ float h2f(unsigned short b) {
    _Float16 h;
    __builtin_memcpy(&h, &b, 2);
    return (float)h;
}
// ELL entry: low16 = src node id (n < 65536), high16 = fp16 edge weight
__device__ __forceinline__ unsigned int pack_e(int src, float w) {
    return (unsigned int)src | ((unsigned int)f2h(w) << 16);
}

// Shared ELL-gather core: one node per 16-lane group (gw = group-in-wave 0..3).
// Metadata loaded coalesced 16 slots at a time, distributed via __shfl; edge rows
// consumed in QUADS with a 1-deep (4-row) prefetch pipeline -> up to 8 rows in
// flight per group to hide L2/L3 latency. OOB meta slots are 0 (weight fp16(0)=0)
// so padding loads are harmless row-0 reads.
__device__ __forceinline__ void ell_gather_acc(
    const unsigned int* __restrict__ bucket, int m,
    const unsigned short* __restrict__ tab, int j8, int gw, int l16,
    float acc[8]) {
    for (int base = 0; base < m; base += 16) {
        const unsigned int mt = (base + l16 < m) ? bucket[base + l16] : 0u;
        const int c16   = min(m - base, 16);
        const int quads = (c16 + 3) >> 2;
        unsigned int u[4];
        ushort8 v[4];
        #pragma unroll
        for (int i = 0; i < 4; ++i) {
            u[i] = __shfl(mt, gw * 16 + i);
            v[i] = *(const ushort8*)&tab[(size_t)(u[i] & 0xFFFFu) * 128 + j8];
        }
        for (int q = 1; q < quads; ++q) {
            unsigned int nu[4];
            ushort8 nv[4];
            #pragma unroll
            for (int i = 0; i < 4; ++i) {
                nu[i] = __shfl(mt, gw * 16 + q * 4 + i);
                nv[i] = *(const ushort8*)&tab[(size_t)(nu[i] & 0xFFFFu) * 128 + j8];
            }
            #pragma unroll
            for (int i = 0; i < 4; ++i) {
                const float f = h2f((unsigned short)(u[i] >> 16));
                #pragma unroll
                for (int k = 0; k < 8; ++k) acc[k] = fmaf(f, bf2f(v[i][k]), acc[k]);
            }
            #pragma unroll
            for (int i = 0; i < 4; ++i) { u[i] = nu[i]; v[i] = nv[i]; }
        }
        #pragma unroll
        for (int i = 0; i < 4; ++i) {
            const float f = h2f((unsigned short)(u[i] >> 16));
            #pragma unroll
            for (int k = 0; k < 8; ++k) acc[k] = fmaf(f, bf2f(v[i][k]), acc[k]);
        }
    }
}

// ---------------- prep: zero cnt + transpose/convert W1,W2 to bf16 [N][K] ----------------
__global__ void k_prep(int* __restrict__ cnt, int n,
                       const float* __restrict__ W1, unsigned short* __restrict__ w1t,
                       const float* __restrict__ W2, unsigned short* __restrict__ w2t) {
    const int i = blockIdx.x * 256 + threadIdx.x;
    if (i < n) cnt[i] = 0;
    if (i < IN_DIM * HID) {                      // W1[128][256] -> w1t[256][128]
        const int k = i / HID, nn = i % HID;
        w1t[(size_t)nn * IN_DIM + k] = f2bf(W1[i]);
    }
    if (i < HID * OUT_DIM) {                     // W2[256][128] -> w2t[128][256]
        const int k = i / OUT_DIM, nn = i % OUT_DIM;
        w2t[(size_t)nn * HID + k] = f2bf(W2[i]);
    }
}

// ---------------- ELL fill: 4 edges per thread, 4 independent atomic chains ----------------
__global__ void k_fill_ell(const int* __restrict__ row, const int* __restrict__ col,
                           const float* __restrict__ ew, int* __restrict__ cnt,
                           unsigned int* __restrict__ ell, int E) {
    const int i  = blockIdx.x * blockDim.x + threadIdx.x;
    const int e0 = i * 4;
    if (e0 + 3 < E) {
        const int4   c4 = *reinterpret_cast<const int4*>(col + e0);
        const int4   r4 = *reinterpret_cast<const int4*>(row + e0);
        const float4 w4 = *reinterpret_cast<const float4*>(ew + e0);
        const int p0 = atomicAdd(&cnt[c4.x], 1);
        const int p1 = atomicAdd(&cnt[c4.y], 1);
        const int p2 = atomicAdd(&cnt[c4.z], 1);
        const int p3 = atomicAdd(&cnt[c4.w], 1);
        if (p0 < ELL_W) ell[(size_t)c4.x * ELL_W + p0] = pack_e(r4.x, w4.x);
        if (p1 < ELL_W) ell[(size_t)c4.y * ELL_W + p1] = pack_e(r4.y, w4.y);
        if (p2 < ELL_W) ell[(size_t)c4.z * ELL_W + p2] = pack_e(r4.z, w4.z);
        if (p3 < ELL_W) ell[(size_t)c4.w * ELL_W + p3] = pack_e(r4.w, w4.w);
    } else {
        for (int e = e0; e < E; ++e) {
            const int c = col[e];
            const int p = atomicAdd(&cnt[c], 1);
            if (p < ELL_W) ell[(size_t)c * ELL_W + p] = pack_e(row[e], ew[e]);
        }
    }
}

// ---------------- fused: deg reduce -> dinv; xs = bf16(dinv * x) (wave per node) ----------------
__global__ __launch_bounds__(256)
void k_deg_xs(const int* __restrict__ cnt, const unsigned int* __restrict__ ell,
              const float* __restrict__ x, float* __restrict__ dinv,
              unsigned short* __restrict__ xs, int n) {
    const int wave = threadIdx.x >> 6;
    const int lane = threadIdx.x & 63;
    const int node = blockIdx.x * 4 + wave;
    if (node >= n) return;
    const int m = min(cnt[node], ELL_W);
    float s = (lane < m) ? h2f((unsigned short)(ell[(size_t)node * ELL_W + lane] >> 16)) : 0.f;
    #pragma unroll
    for (int d = 32; d; d >>= 1) s += __shfl_xor(s, d);
    const float di = rsqrtf(1.0f + s);           // self-loop weight 1
    if (lane == 0) dinv[node] = di;
    const float2 v = *reinterpret_cast<const float2*>(x + (size_t)node * IN_DIM + lane * 2);
    const unsigned int packed = (unsigned int)f2bf(v.x * di) |
                                ((unsigned int)f2bf(v.y * di) << 16);
    *reinterpret_cast<unsigned int*>(xs + (size_t)node * IN_DIM + lane * 2) = packed;
}

// ---------------- gather: node per 16-lane group, 16 nodes/block (F=128) ----------------
// hs rows pre-scaled by dinv[src]. out[c] = post( dinv[c]*(hs[c] + sum ew*hs[src]) )
template<bool BIAS_RELU, bool BF16OUT>
__global__ __launch_bounds__(256)
void k_gather_w(const int* __restrict__ cnt, const unsigned int* __restrict__ ell,
                const float* __restrict__ dinv, const unsigned short* __restrict__ hs,
                const float* __restrict__ bias, void* __restrict__ out_, int n) {
    constexpr int F = 128;
    const int gid  = threadIdx.x >> 4;           // 0..15 group in block
    const int gw   = gid & 3;                    // group in wave
    const int l16  = threadIdx.x & 15;
    const int j8   = l16 * 8;
    const int node = blockIdx.x * 16 + gid;
    if (node >= n) return;

    const int m = min(cnt[node], ELL_W);
    const unsigned int* bucket = ell + (size_t)node * ELL_W;

    // issue self-row + dinv early so they overlap the gather pipeline
    const float dc = dinv[node];
    const ushort8 hv = *reinterpret_cast<const ushort8*>(hs + (size_t)node * F + j8);

    float acc[8] = {};
    ell_gather_acc(bucket, m, hs, j8, gw, l16, acc);

    float o[8];
    if (BIAS_RELU) {
        const float4 b0 = *reinterpret_cast<const float4*>(bias + j8);
        const float4 b1 = *reinterpret_cast<const float4*>(bias + j8 + 4);
        const float bb[8] = {b0.x, b0.y, b0.z, b0.w, b1.x, b1.y, b1.z, b1.w};
        #pragma unroll
        for (int i = 0; i < 8; ++i)
            o[i] = fmaxf(fmaf(dc, acc[i] + bf2f(hv[i]), bb[i]), 0.f);
    } else {
        #pragma unroll
        for (int i = 0; i < 8; ++i) o[i] = dc * (acc[i] + bf2f(hv[i]));
    }
    if (BF16OUT) {
        unsigned short ob[8];
        #pragma unroll
        for (int i = 0; i < 8; ++i) ob[i] = f2bf(o[i]);
        *reinterpret_cast<uint4*>((unsigned short*)out_ + (size_t)node * F + j8) =
            *reinterpret_cast<uint4*>(ob);
    } else {
        float* op = (float*)out_ + (size_t)node * F + j8;
        *reinterpret_cast<float4*>(op)     = make_float4(o[0], o[1], o[2], o[3]);
        *reinterpret_cast<float4*>(op + 4) = make_float4(o[4], o[5], o[6], o[7]);
    }
}

// ---- GEMM1: H1 = relu(A @ W1t^T + b1), weight fragments resident in VGPRs ----
// Block = 256 thr (4 waves), tile = 32 rows x 256 cols, K = 128. Wave w owns the
// 64-col stripe w*64. W1-frags (64 VGPR) loaded once; per tile only the 8 KB
// A-slab is staged (double-buffered, rule-21 XOR swizzle). Output bounced
// through LDS for coalesced 16B stores.
__global__ __launch_bounds__(256)
void k_gemm1(const unsigned short* __restrict__ A,    // aggx [Mpad][128] bf16
             const unsigned short* __restrict__ W1t,  // [256][128] bf16
             const float* __restrict__ b1,
             unsigned short* __restrict__ H1,         // [Mpad][256] bf16
             int ntiles) {
    __shared__ unsigned short As[2][32 * 128];   // 2 x 8 KB
    __shared__ unsigned short Hs[32 * 256];      // 16 KB

    const int t    = threadIdx.x;
    const int w    = t >> 6;
    const int lane = t & 63;
    const int quad = lane >> 4;
    const int l16  = lane & 15;
    const int xr   = (l16 & 7) << 3;

    short8 bw[4][4];
    #pragma unroll
    for (int nt = 0; nt < 4; ++nt)
        #pragma unroll
        for (int ks = 0; ks < 4; ++ks)
            bw[nt][ks] = *(const short8*)&W1t[(size_t)(w * 64 + nt * 16 + l16) * 128 + ks * 32 + quad * 8];
    float bv[4];
    #pragma unroll
    for (int nt = 0; nt < 4; ++nt) bv[nt] = b1[w * 64 + nt * 16 + l16];

    auto stage = [&](int buf, int tile) {        // [32][128], source pre-swizzled
        #pragma unroll
        for (int j = 0; j < 2; ++j) {
            const int ci = j * 256 + t;          // 512 16B-chunks
            const int r  = ci >> 4;
            const int c  = (ci & 15) ^ (r & 7);
            __builtin_amdgcn_global_load_lds(
                (const __attribute__((address_space(1))) uint32_t*)(A + ((size_t)tile * 32 + r) * 128 + c * 8),
                (__attribute__((address_space(3))) uint32_t*)(&As[buf][ci * 8]), 16, 0, 0);
        }
    };
    auto mma = [&](int buf, f32x4 (&acc)[2][4]) {
        #pragma unroll
        for (int ks = 0; ks < 4; ++ks) {
            short8 af[2];
            #pragma unroll
            for (int mt = 0; mt < 2; ++mt)
                af[mt] = *(const short8*)&As[buf][(mt * 16 + l16) * 128 + ((ks * 32 + quad * 8) ^ xr)];
            #pragma unroll
            for (int mt = 0; mt < 2; ++mt)
                #pragma unroll
                for (int nt = 0; nt < 4; ++nt)
                    acc[mt][nt] = __builtin_amdgcn_mfma_f32_16x16x32_bf16(
                        af[mt], bw[nt][ks], acc[mt][nt], 0, 0, 0);
        }
    };
    auto epi_store = [&](f32x4 (&acc)[2][4]) {   // bias+relu -> Hs (bank-swizzled)
        #pragma unroll
        for (int mt = 0; mt < 2; ++mt)
            #pragma unroll
            for (int i = 0; i < 4; ++i) {
                const int r  = mt * 16 + quad * 4 + i;
                const int xw = (r & 7) << 3;
                #pragma unroll
                for (int nt = 0; nt < 4; ++nt) {
                    const int col = w * 64 + nt * 16 + l16;
                    Hs[r * 256 + (col ^ xw)] = f2bf(fmaxf(acc[mt][nt][i] + bv[nt], 0.f));
                }
            }
    };
    auto copy_out = [&](int tile) {              // Hs -> H1, 16B coalesced, unswizzle
        #pragma unroll
        for (int j = 0; j < 4; ++j) {
            const int ci = j * 256 + t;          // 1024 chunks
            const int r  = ci >> 5;
            const int cr = ci & 31;
            *(uint4*)&H1[((size_t)tile * 32 + r) * 256 + cr * 8] =
                *(const uint4*)&Hs[r * 256 + ((cr ^ (r & 7)) * 8)];
        }
    };

    const int t0 = blockIdx.x;
    const int t1 = blockIdx.x + gridDim.x;

    stage(0, t0);
    __syncthreads();                             // buf0 ready
    if (t1 < ntiles) stage(1, t1);               // in flight under tile-0 work
    {
        f32x4 acc[2][4] = {};
        mma(0, acc);
        epi_store(acc);
    }
    __syncthreads();                             // Hs visible; buf1 drained
    copy_out(t0);
    if (t1 < ntiles) {
        f32x4 acc[2][4] = {};
        mma(1, acc);
        __syncthreads();                         // copy_out reads done before Hs reuse
        epi_store(acc);
        __syncthreads();
        copy_out(t1);
    }
}

// ---- GEMM2: H2 = dinv * (H1 @ W2t^T), weight fragments resident in VGPRs ----
// Tile = 32 rows x 128 cols, K = 256. Wave w owns the 32-col stripe w*32.
__global__ __launch_bounds__(256)
void k_gemm2(const unsigned short* __restrict__ H1,   // [Mpad][256] bf16
             const unsigned short* __restrict__ W2t,  // [128][256] bf16
             const float* __restrict__ dinv,
             unsigned short* __restrict__ H2,         // [Mpad][128] bf16
             int n, int ntiles) {
    __shared__ unsigned short As[2][32 * 256];   // 2 x 16 KB
    __shared__ unsigned short Hs[32 * 128];      // 8 KB

    const int t    = threadIdx.x;
    const int w    = t >> 6;
    const int lane = t & 63;
    const int quad = lane >> 4;
    const int l16  = lane & 15;
    const int xr   = (l16 & 7) << 3;

    short8 bw[2][8];
    #pragma unroll
    for (int nt = 0; nt < 2; ++nt)
        #pragma unroll
        for (int ks = 0; ks < 8; ++ks)
            bw[nt][ks] = *(const short8*)&W2t[(size_t)(w * 32 + nt * 16 + l16) * 256 + ks * 32 + quad * 8];

    auto stage = [&](int buf, int tile) {        // [32][256], source pre-swizzled
        #pragma unroll
        for (int j = 0; j < 4; ++j) {
            const int ci = j * 256 + t;          // 1024 16B-chunks
            const int r  = ci >> 5;
            const int c  = (ci & 31) ^ (r & 7);
            __builtin_amdgcn_global_load_lds(
                (const __attribute__((address_space(1))) uint32_t*)(H1 + ((size_t)tile * 32 + r) * 256 + c * 8),
                (__attribute__((address_space(3))) uint32_t*)(&As[buf][ci * 8]), 16, 0, 0);
        }
    };
    auto mma = [&](int buf, f32x4 (&acc)[2][2]) {
        #pragma unroll
        for (int ks = 0; ks < 8; ++ks) {
            short8 af[2];
            #pragma unroll
            for (int mt = 0; mt < 2; ++mt)
                af[mt] = *(const short8*)&As[buf][(mt * 16 + l16) * 256 + ((ks * 32 + quad * 8) ^ xr)];
            #pragma unroll
            for (int mt = 0; mt < 2; ++mt)
                #pragma unroll
                for (int nt = 0; nt < 2; ++nt)
                    acc[mt][nt] = __builtin_amdgcn_mfma_f32_16x16x32_bf16(
                        af[mt], bw[nt][ks], acc[mt][nt], 0, 0, 0);
        }
    };
    auto epi_store = [&](f32x4 (&acc)[2][2], int tile) {
        #pragma unroll
        for (int mt = 0; mt < 2; ++mt)
            #pragma unroll
            for (int i = 0; i < 4; ++i) {
                const int r  = mt * 16 + quad * 4 + i;
                const int rg = tile * 32 + r;
                const float dr = (rg < n) ? dinv[rg] : 0.f;
                const int xw = (r & 7) << 3;
                #pragma unroll
                for (int nt = 0; nt < 2; ++nt) {
                    const int col = w * 32 + nt * 16 + l16;
                    Hs[r * 128 + (col ^ xw)] = f2bf(acc[mt][nt][i] * dr);
                }
            }
    };
    auto copy_out = [&](int tile) {
        #pragma unroll
        for (int j = 0; j < 2; ++j) {
            const int ci = j * 256 + t;          // 512 chunks
            const int r  = ci >> 4;
            const int cr = ci & 15;
            *(uint4*)&H2[((size_t)tile * 32 + r) * 128 + cr * 8] =
                *(const uint4*)&Hs[r * 128 + ((cr ^ (r & 7)) * 8)];
        }
    };

    const int t0 = blockIdx.x;
    const int t1 = blockIdx.x + gridDim.x;

    stage(0, t0);
    __syncthreads();
    if (t1 < ntiles) stage(1, t1);
    {
        f32x4 acc[2][2] = {};
        mma(0, acc);
        epi_store(acc, t0);
    }
    __syncthreads();
    copy_out(t0);
    if (t1 < ntiles) {
        f32x4 acc[2][2] = {};
        mma(1, acc);
        __syncthreads();
        epi_store(acc, t1);
        __syncthreads();
        copy_out(t1);
    }
}

// ---------------- launch ----------------
extern "C" void kernel_launch(void* const* d_in, const int* in_sizes, int n_in,
                              void* d_out, int out_size, void* d_ws, size_t ws_size,
                              hipStream_t stream) {
    const float* x  = (const float*)d_in[0];
    const int*   ei = (const int*)d_in[1];
    const float* ew = (const float*)d_in[2];
    const float* W1 = (const float*)d_in[3];
    const float* b1 = (const float*)d_in[4];
    const float* W2 = (const float*)d_in[5];
    const float* b2 = (const float*)d_in[6];
    float* out = (float*)d_out;

    const int n = in_sizes[0] / IN_DIM;     // 50000  (< 65536, required by ELL packing)
    const int E = in_sizes[1] / 2;          // 600000
    const int Mpad = (n + 127) & ~127;      // 50048
    const int ntiles = Mpad / 32;           // 1564 (even)
    const int* row = ei;
    const int* col = ei + E;

    float* ws = (float*)d_ws;
    size_t o = 0;
    auto alloc = [&](size_t words) { float* p = ws + o; o += (words + 63) & ~(size_t)63; return p; };
    float* dinv = alloc(n);
    int*   cnt  = (int*)alloc(n);
    unsigned int* ell = (unsigned int*)alloc((size_t)n * ELL_W);                  // 12.8 MB
    unsigned short* xs   = (unsigned short*)alloc((size_t)Mpad * IN_DIM / 2);     // bf16 dinv*x
    unsigned short* aggx = (unsigned short*)alloc((size_t)Mpad * IN_DIM / 2);     // bf16 A-hat x
    unsigned short* h1   = (unsigned short*)alloc((size_t)Mpad * HID / 2);        // bf16
    unsigned short* h2s  = (unsigned short*)alloc((size_t)Mpad * OUT_DIM / 2);    // bf16 dinv*h2
    unsigned short* w1t  = (unsigned short*)alloc((size_t)IN_DIM * HID / 2);
    unsigned short* w2t  = (unsigned short*)alloc((size_t)HID * OUT_DIM / 2);

    // ---- build ----
    k_prep<<<(n + 255) / 256, 256, 0, stream>>>(cnt, n, W1, w1t, W2, w2t);
    k_fill_ell<<<(E / 4 + 255) / 256, 256, 0, stream>>>(row, col, ew, cnt, ell, E);
    k_deg_xs<<<(n + 3) / 4, 256, 0, stream>>>(cnt, ell, x, dinv, xs, n);

    // ---- layer 1 aggregate: aggx = dinv*(xs_self + sum ew*xs) ----
    k_gather_w<false, true><<<(n + 15) / 16, 256, 0, stream>>>(cnt, ell, dinv, xs, nullptr, aggx, n);

    // ---- weight-resident GEMMs: h1 = relu(aggx@W1+b1); h2s = dinv*(h1@W2) ----
    k_gemm1<<<ntiles / 2, 256, 0, stream>>>(aggx, w1t, b1, h1, ntiles);
    k_gemm2<<<ntiles / 2, 256, 0, stream>>>(h1, w2t, dinv, h2s, n, ntiles);

    // ---- layer 2 aggregate + bias + relu ----
    k_gather_w<true, false><<<(n + 15) / 16, 256, 0, stream>>>(cnt, ell, dinv, h2s, b2, out, n);
}

// Round 5
// 204.509 us; speedup vs baseline: 1.1226x; 1.0153x over previous
//
#include <hip/hip_runtime.h>
#include <hip/hip_bf16.h>

constexpr int IN_DIM  = 128;
constexpr int HID     = 256;
constexpr int OUT_DIM = 128;
constexpr int ELL_W   = 64;    // max in-degree slots; Poisson(12) => P(overflow) ~ 1e-24

typedef __attribute__((ext_vector_type(8))) short short8;
typedef __attribute__((ext_vector_type(8))) unsigned short ushort8;
typedef __attribute__((ext_vector_type(4))) float f32x4;

__device__ __forceinline__ float bf2f(unsigned short u) {
    return __uint_as_float(((unsigned int)u) << 16);
}
__device__ __forceinline__ unsigned short f2bf(float f) {
    unsigned int u = __float_as_uint(f);
    u += 0x7FFFu + ((u >> 16) & 1u);      // RNE
    return (unsigned short)(u >> 16);
}
__device__ __forceinline__ unsigned short f2h(float f) {
    _Float16 h = (_Float16)f;             // v_cvt_f16_f32, RNE
    unsigned short b;
    __builtin_memcpy(&b, &h, 2);
    return b;
}
__device__ __forceinline__ float h2f(unsigned short b) {
    _Float16 h;
    __builtin_memcpy(&h, &b, 2);
    return (float)h;
}
// ELL entry: low16 = src node id (n < 65536), high16 = fp16 edge weight
__device__ __forceinline__ unsigned int pack_e(int src, float w) {
    return (unsigned int)src | ((unsigned int)f2h(w) << 16);
}

// Shared ELL-gather core: one node per 16-lane group (gw = group-in-wave 0..3).
// Metadata loaded coalesced 16 slots at a time, distributed via __shfl; edge rows
// consumed in QUADS with a 1-deep (4-row) prefetch pipeline -> up to 8 rows in
// flight per group to hide L2/L3 latency. OOB meta slots are 0 (weight fp16(0)=0)
// so padding loads are harmless row-0 reads (same line chip-wide -> L2-cached).
__device__ __forceinline__ void ell_gather_acc(
    const unsigned int* __restrict__ bucket, int m,
    const unsigned short* __restrict__ tab, int j8, int gw, int l16,
    float acc[8]) {
    for (int base = 0; base < m; base += 16) {
        const unsigned int mt = (base + l16 < m) ? bucket[base + l16] : 0u;
        const int c16   = min(m - base, 16);
        const int quads = (c16 + 3) >> 2;
        unsigned int u[4];
        ushort8 v[4];
        #pragma unroll
        for (int i = 0; i < 4; ++i) {
            u[i] = __shfl(mt, gw * 16 + i);
            v[i] = *(const ushort8*)&tab[(size_t)(u[i] & 0xFFFFu) * 128 + j8];
        }
        for (int q = 1; q < quads; ++q) {
            unsigned int nu[4];
            ushort8 nv[4];
            #pragma unroll
            for (int i = 0; i < 4; ++i) {
                nu[i] = __shfl(mt, gw * 16 + q * 4 + i);
                nv[i] = *(const ushort8*)&tab[(size_t)(nu[i] & 0xFFFFu) * 128 + j8];
            }
            #pragma unroll
            for (int i = 0; i < 4; ++i) {
                const float f = h2f((unsigned short)(u[i] >> 16));
                #pragma unroll
                for (int k = 0; k < 8; ++k) acc[k] = fmaf(f, bf2f(v[i][k]), acc[k]);
            }
            #pragma unroll
            for (int i = 0; i < 4; ++i) { u[i] = nu[i]; v[i] = nv[i]; }
        }
        #pragma unroll
        for (int i = 0; i < 4; ++i) {
            const float f = h2f((unsigned short)(u[i] >> 16));
            #pragma unroll
            for (int k = 0; k < 8; ++k) acc[k] = fmaf(f, bf2f(v[i][k]), acc[k]);
        }
    }
}

// ---------------- prep: zero cnt + transpose/convert W1,W2 to bf16 [N][K] ----------------
__global__ void k_prep(int* __restrict__ cnt, int n,
                       const float* __restrict__ W1, unsigned short* __restrict__ w1t,
                       const float* __restrict__ W2, unsigned short* __restrict__ w2t) {
    const int i = blockIdx.x * 256 + threadIdx.x;
    if (i < n) cnt[i] = 0;
    if (i < IN_DIM * HID) {                      // W1[128][256] -> w1t[256][128]
        const int k = i / HID, nn = i % HID;
        w1t[(size_t)nn * IN_DIM + k] = f2bf(W1[i]);
    }
    if (i < HID * OUT_DIM) {                     // W2[256][128] -> w2t[128][256]
        const int k = i / OUT_DIM, nn = i % OUT_DIM;
        w2t[(size_t)nn * HID + k] = f2bf(W2[i]);
    }
}

// ---------------- ELL fill: 4 edges per thread, 4 independent atomic chains ----------------
// ELL scatter stores are nontemporal: 4B random scatters cause partial-line
// ownership churn in L2; streaming them avoids the RMW amplification
// (round-3 evidence: WRITE_SIZE 54 MB at ~1 TB/s effective for this kernel).
__global__ void k_fill_ell(const int* __restrict__ row, const int* __restrict__ col,
                           const float* __restrict__ ew, int* __restrict__ cnt,
                           unsigned int* __restrict__ ell, int E) {
    const int i  = blockIdx.x * blockDim.x + threadIdx.x;
    const int e0 = i * 4;
    if (e0 + 3 < E) {
        const int4   c4 = *reinterpret_cast<const int4*>(col + e0);
        const int4   r4 = *reinterpret_cast<const int4*>(row + e0);
        const float4 w4 = *reinterpret_cast<const float4*>(ew + e0);
        const int p0 = atomicAdd(&cnt[c4.x], 1);
        const int p1 = atomicAdd(&cnt[c4.y], 1);
        const int p2 = atomicAdd(&cnt[c4.z], 1);
        const int p3 = atomicAdd(&cnt[c4.w], 1);
        if (p0 < ELL_W) __builtin_nontemporal_store(pack_e(r4.x, w4.x), &ell[(size_t)c4.x * ELL_W + p0]);
        if (p1 < ELL_W) __builtin_nontemporal_store(pack_e(r4.y, w4.y), &ell[(size_t)c4.y * ELL_W + p1]);
        if (p2 < ELL_W) __builtin_nontemporal_store(pack_e(r4.z, w4.z), &ell[(size_t)c4.z * ELL_W + p2]);
        if (p3 < ELL_W) __builtin_nontemporal_store(pack_e(r4.w, w4.w), &ell[(size_t)c4.w * ELL_W + p3]);
    } else {
        for (int e = e0; e < E; ++e) {
            const int c = col[e];
            const int p = atomicAdd(&cnt[c], 1);
            if (p < ELL_W) __builtin_nontemporal_store(pack_e(row[e], ew[e]), &ell[(size_t)c * ELL_W + p]);
        }
    }
}

// ---------------- fused: deg reduce -> dinv; xs = bf16(dinv * x) (wave per node) ----------------
__global__ __launch_bounds__(256)
void k_deg_xs(const int* __restrict__ cnt, const unsigned int* __restrict__ ell,
              const float* __restrict__ x, float* __restrict__ dinv,
              unsigned short* __restrict__ xs, int n) {
    const int wave = threadIdx.x >> 6;
    const int lane = threadIdx.x & 63;
    const int node = blockIdx.x * 4 + wave;
    if (node >= n) return;
    const int m = min(cnt[node], ELL_W);
    float s = (lane < m) ? h2f((unsigned short)(ell[(size_t)node * ELL_W + lane] >> 16)) : 0.f;
    #pragma unroll
    for (int d = 32; d; d >>= 1) s += __shfl_xor(s, d);
    const float di = rsqrtf(1.0f + s);           // self-loop weight 1
    if (lane == 0) dinv[node] = di;
    const float2 v = *reinterpret_cast<const float2*>(x + (size_t)node * IN_DIM + lane * 2);
    const unsigned int packed = (unsigned int)f2bf(v.x * di) |
                                ((unsigned int)f2bf(v.y * di) << 16);
    *reinterpret_cast<unsigned int*>(xs + (size_t)node * IN_DIM + lane * 2) = packed;
}

// ---------------- gather: node per 16-lane group, 16 nodes/block (F=128) ----------------
// hs rows pre-scaled by dinv[src]. out[c] = post( dinv[c]*(hs[c] + sum ew*hs[src]) )
template<bool BIAS_RELU, bool BF16OUT>
__global__ __launch_bounds__(256)
void k_gather_w(const int* __restrict__ cnt, const unsigned int* __restrict__ ell,
                const float* __restrict__ dinv, const unsigned short* __restrict__ hs,
                const float* __restrict__ bias, void* __restrict__ out_, int n) {
    constexpr int F = 128;
    const int gid  = threadIdx.x >> 4;           // 0..15 group in block
    const int gw   = gid & 3;                    // group in wave
    const int l16  = threadIdx.x & 15;
    const int j8   = l16 * 8;
    const int node = blockIdx.x * 16 + gid;
    if (node >= n) return;

    const int m = min(cnt[node], ELL_W);
    const unsigned int* bucket = ell + (size_t)node * ELL_W;

    // issue self-row + dinv early so they overlap the gather pipeline
    const float dc = dinv[node];
    const ushort8 hv = *reinterpret_cast<const ushort8*>(hs + (size_t)node * F + j8);

    float acc[8] = {};
    ell_gather_acc(bucket, m, hs, j8, gw, l16, acc);

    float o[8];
    if (BIAS_RELU) {
        const float4 b0 = *reinterpret_cast<const float4*>(bias + j8);
        const float4 b1 = *reinterpret_cast<const float4*>(bias + j8 + 4);
        const float bb[8] = {b0.x, b0.y, b0.z, b0.w, b1.x, b1.y, b1.z, b1.w};
        #pragma unroll
        for (int i = 0; i < 8; ++i)
            o[i] = fmaxf(fmaf(dc, acc[i] + bf2f(hv[i]), bb[i]), 0.f);
    } else {
        #pragma unroll
        for (int i = 0; i < 8; ++i) o[i] = dc * (acc[i] + bf2f(hv[i]));
    }
    if (BF16OUT) {
        unsigned short ob[8];
        #pragma unroll
        for (int i = 0; i < 8; ++i) ob[i] = f2bf(o[i]);
        *reinterpret_cast<uint4*>((unsigned short*)out_ + (size_t)node * F + j8) =
            *reinterpret_cast<uint4*>(ob);
    } else {
        float* op = (float*)out_ + (size_t)node * F + j8;
        *reinterpret_cast<float4*>(op)     = make_float4(o[0], o[1], o[2], o[3]);
        *reinterpret_cast<float4*>(op + 4) = make_float4(o[4], o[5], o[6], o[7]);
    }
}

// ---- fused weight-resident dual GEMM: H2 = dinv * (relu(A@W1t^T + b1) @ W2t^T) ----
// Block = 256 thr (4 waves), TPB=4 tiles of 32 rows each. W1 frags (64 VGPR) +
// W2 frags (64 VGPR) resident for the whole block -> weight re-reads amortized
// over 128 rows. h1 tile lives only in LDS (no 51 MB global round-trip).
// A-slabs double-buffered via global_load_lds with rule-21 XOR swizzle; outputs
// bounced through LDS (Os) for coalesced 16B stores.
__global__ __launch_bounds__(256, 2)
void k_gemm_fused(const unsigned short* __restrict__ A,    // aggx [Mpad][128] bf16
                  const unsigned short* __restrict__ W1t,  // [256][128] bf16
                  const unsigned short* __restrict__ W2t,  // [128][256] bf16
                  const float* __restrict__ b1,
                  const float* __restrict__ dinv,
                  unsigned short* __restrict__ H2,         // h2s [Mpad][128] bf16
                  int n, int tpb) {
    __shared__ unsigned short As[2][32 * 128];   // 2 x 8 KB  A-slab double buffer
    __shared__ unsigned short Hs[32 * 256];      // 16 KB     h1 tile (bf16, swizzled)
    __shared__ unsigned short Os[32 * 128];      // 8 KB      output bounce

    const int t    = threadIdx.x;
    const int w    = t >> 6;
    const int lane = t & 63;
    const int quad = lane >> 4;
    const int l16  = lane & 15;
    const int xr   = (l16 & 7) << 3;

    // resident weight fragments (wave w owns col-stripes w*64 (L1) / w*32 (L2))
    short8 bw1[4][4];
    #pragma unroll
    for (int nt = 0; nt < 4; ++nt)
        #pragma unroll
        for (int ks = 0; ks < 4; ++ks)
            bw1[nt][ks] = *(const short8*)&W1t[(size_t)(w * 64 + nt * 16 + l16) * 128 + ks * 32 + quad * 8];
    short8 bw2[2][8];
    #pragma unroll
    for (int nt = 0; nt < 2; ++nt)
        #pragma unroll
        for (int ks = 0; ks < 8; ++ks)
            bw2[nt][ks] = *(const short8*)&W2t[(size_t)(w * 32 + nt * 16 + l16) * 256 + ks * 32 + quad * 8];
    float bv[4];
    #pragma unroll
    for (int nt = 0; nt < 4; ++nt) bv[nt] = b1[w * 64 + nt * 16 + l16];

    const int tile0 = blockIdx.x * tpb;

    auto stage = [&](int buf, int tile) {        // [32][128], source pre-swizzled
        #pragma unroll
        for (int j = 0; j < 2; ++j) {
            const int ci = j * 256 + t;          // 512 16B-chunks
            const int r  = ci >> 4;
            const int c  = (ci & 15) ^ (r & 7);
            __builtin_amdgcn_global_load_lds(
                (const __attribute__((address_space(1))) uint32_t*)(A + ((size_t)tile * 32 + r) * 128 + c * 8),
                (__attribute__((address_space(3))) uint32_t*)(&As[buf][ci * 8]), 16, 0, 0);
        }
    };

    stage(0, tile0);
    __syncthreads();

    for (int it = 0; it < tpb; ++it) {
        const int tile = tile0 + it;
        if (it + 1 < tpb) stage((it + 1) & 1, tile + 1);

        // ---- layer 1: acc1 = A_tile @ W1^T ----
        f32x4 acc1[2][4] = {};
        #pragma unroll
        for (int ks = 0; ks < 4; ++ks) {
            short8 af[2];
            #pragma unroll
            for (int mt = 0; mt < 2; ++mt)
                af[mt] = *(const short8*)&As[it & 1][(mt * 16 + l16) * 128 + ((ks * 32 + quad * 8) ^ xr)];
            #pragma unroll
            for (int mt = 0; mt < 2; ++mt)
                #pragma unroll
                for (int nt = 0; nt < 4; ++nt)
                    acc1[mt][nt] = __builtin_amdgcn_mfma_f32_16x16x32_bf16(
                        af[mt], bw1[nt][ks], acc1[mt][nt], 0, 0, 0);
        }
        __syncthreads();        // prev iter's Hs reads (mma2) + Os reads (copy_out) done

        // ---- epilogue 1: bias+relu -> Hs (bf16, row-XOR swizzled) ----
        #pragma unroll
        for (int mt = 0; mt < 2; ++mt)
            #pragma unroll
            for (int i = 0; i < 4; ++i) {
                const int r  = mt * 16 + quad * 4 + i;
                const int xw = (r & 7) << 3;
                #pragma unroll
                for (int nt = 0; nt < 4; ++nt) {
                    const int col = w * 64 + nt * 16 + l16;
                    Hs[r * 256 + (col ^ xw)] = f2bf(fmaxf(acc1[mt][nt][i] + bv[nt], 0.f));
                }
            }
        __syncthreads();        // Hs visible

        // ---- layer 2: acc2 = Hs @ W2^T ----
        f32x4 acc2[2][2] = {};
        #pragma unroll
        for (int ks = 0; ks < 8; ++ks) {
            short8 af[2];
            #pragma unroll
            for (int mt = 0; mt < 2; ++mt)
                af[mt] = *(const short8*)&Hs[(mt * 16 + l16) * 256 + ((ks * 32 + quad * 8) ^ xr)];
            #pragma unroll
            for (int mt = 0; mt < 2; ++mt)
                #pragma unroll
                for (int nt = 0; nt < 2; ++nt)
                    acc2[mt][nt] = __builtin_amdgcn_mfma_f32_16x16x32_bf16(
                        af[mt], bw2[nt][ks], acc2[mt][nt], 0, 0, 0);
        }

        // ---- epilogue 2: row-scale by dinv -> Os (swizzled) ----
        #pragma unroll
        for (int mt = 0; mt < 2; ++mt)
            #pragma unroll
            for (int i = 0; i < 4; ++i) {
                const int r  = mt * 16 + quad * 4 + i;
                const int rg = tile * 32 + r;
                const float dr = (rg < n) ? dinv[rg] : 0.f;
                const int xw = (r & 7) << 3;
                #pragma unroll
                for (int nt = 0; nt < 2; ++nt) {
                    const int col = w * 32 + nt * 16 + l16;
                    Os[r * 128 + (col ^ xw)] = f2bf(acc2[mt][nt][i] * dr);
                }
            }
        __syncthreads();        // Os visible (also drains next A-slab stage)

        // ---- copy out: Os -> H2, 16B coalesced, unswizzle ----
        #pragma unroll
        for (int j = 0; j < 2; ++j) {
            const int ci = j * 256 + t;          // 512 chunks
            const int r  = ci >> 4;
            const int cr = ci & 15;
            *(uint4*)&H2[((size_t)tile * 32 + r) * 128 + cr * 8] =
                *(const uint4*)&Os[r * 128 + ((cr ^ (r & 7)) * 8)];
        }
    }
}

// ---------------- launch ----------------
extern "C" void kernel_launch(void* const* d_in, const int* in_sizes, int n_in,
                              void* d_out, int out_size, void* d_ws, size_t ws_size,
                              hipStream_t stream) {
    const float* x  = (const float*)d_in[0];
    const int*   ei = (const int*)d_in[1];
    const float* ew = (const float*)d_in[2];
    const float* W1 = (const float*)d_in[3];
    const float* b1 = (const float*)d_in[4];
    const float* W2 = (const float*)d_in[5];
    const float* b2 = (const float*)d_in[6];
    float* out = (float*)d_out;

    const int n = in_sizes[0] / IN_DIM;     // 50000  (< 65536, required by ELL packing)
    const int E = in_sizes[1] / 2;          // 600000
    const int Mpad = (n + 127) & ~127;      // 50048
    const int ntiles = Mpad / 32;           // 1564
    const int TPB = 4;                      // tiles per block (1564 = 391*4 exactly)
    const int* row = ei;
    const int* col = ei + E;

    float* ws = (float*)d_ws;
    size_t o = 0;
    auto alloc = [&](size_t words) { float* p = ws + o; o += (words + 63) & ~(size_t)63; return p; };
    float* dinv = alloc(n);
    int*   cnt  = (int*)alloc(n);
    unsigned int* ell = (unsigned int*)alloc((size_t)n * ELL_W);                  // 12.8 MB
    unsigned short* xs   = (unsigned short*)alloc((size_t)Mpad * IN_DIM / 2);     // bf16 dinv*x
    unsigned short* aggx = (unsigned short*)alloc((size_t)Mpad * IN_DIM / 2);     // bf16 A-hat x
    unsigned short* h2s  = (unsigned short*)alloc((size_t)Mpad * OUT_DIM / 2);    // bf16 dinv*h2
    unsigned short* w1t  = (unsigned short*)alloc((size_t)IN_DIM * HID / 2);
    unsigned short* w2t  = (unsigned short*)alloc((size_t)HID * OUT_DIM / 2);

    // ---- build ----
    k_prep<<<(n + 255) / 256, 256, 0, stream>>>(cnt, n, W1, w1t, W2, w2t);
    k_fill_ell<<<(E / 4 + 255) / 256, 256, 0, stream>>>(row, col, ew, cnt, ell, E);
    k_deg_xs<<<(n + 3) / 4, 256, 0, stream>>>(cnt, ell, x, dinv, xs, n);

    // ---- layer 1 aggregate: aggx = dinv*(xs_self + sum ew*xs) ----
    k_gather_w<false, true><<<(n + 15) / 16, 256, 0, stream>>>(cnt, ell, dinv, xs, nullptr, aggx, n);

    // ---- fused weight-resident GEMMs: h2s = dinv*(relu(aggx@W1+b1)@W2) ----
    k_gemm_fused<<<ntiles / TPB, 256, 0, stream>>>(aggx, w1t, w2t, b1, dinv, h2s, n, TPB);

    // ---- layer 2 aggregate + bias + relu ----
    k_gather_w<true, false><<<(n + 15) / 16, 256, 0, stream>>>(cnt, ell, dinv, h2s, b2, out, n);
}